// Round 10
// baseline (176.104 us; speedup 1.0000x reference)
//
#include <hip/hip_runtime.h>

using u32 = unsigned int;
typedef int v4i __attribute__((ext_vector_type(4)));

// ===== geometry =====
constexpr int N_IMG   = 16;
constexpr int PADROW  = 4096;   // 64 px * 64 ch bytes
constexpr int ROWS_PI = 58;     // 56 real + top/bottom pad

// ===== workspace layout (bytes) =====
constexpr size_t OFS_QX   = 4096;
constexpr size_t SZ_QPAD  = (size_t)(1 + N_IMG * ROWS_PI) * PADROW;
constexpr size_t OFS_Q1   = OFS_QX + SZ_QPAD;
constexpr size_t OFS_O1   = OFS_Q1 + SZ_QPAD;
constexpr size_t SZ_OF    = (size_t)N_IMG * 56 * 56 * 64 * 4;
constexpr size_t OFS_O2   = OFS_O1 + SZ_OF;
constexpr size_t OFS_QW1  = OFS_O2 + SZ_OF;
constexpr size_t OFS_QW2  = OFS_QW1 + 36864;
constexpr size_t OFS_WB1  = OFS_QW2 + 36864;
constexpr size_t OFS_WB2  = OFS_WB1 + 18432;
constexpr size_t OFS_WSUM = OFS_WB2 + 18432;      // 64 ints (zeroed)
constexpr size_t OFS_SCAL = OFS_WSUM + 256;       // maxX/maxW1/maxW2 @0; rmax1 @+128; rmax2 @+256 (zeroed)
constexpr size_t OFS_STX  = OFS_SCAL + 384;       // 4608 ints (zeroed)
constexpr size_t OFS_STQ  = OFS_STX + 18432;      // 4608 ints (zeroed)
constexpr size_t OFS_WSRED= OFS_STQ + 18432;      // 1024 floats absmax partials (all overwritten)
constexpr size_t WS_NEED  = OFS_WSRED + 4096;
constexpr size_t ZSPAN    = OFS_WSRED - OFS_WSUM; // memset: wsum+scal+stx+stq (37.5 KB)
constexpr size_t OUTN     = (size_t)16 * 64 * 56 * 56;

// ===== helpers =====
static __device__ __forceinline__ float block_redmax(float v, float* red, int t) {
    red[t] = v; __syncthreads();
    for (int s = 128; s > 0; s >>= 1) {
        if (t < s) red[t] = fmaxf(red[t], red[t + s]);
        __syncthreads();
    }
    float r = red[0]; __syncthreads();
    return r;
}

// ===== K1: weight quant on blocks 0..17 (launch first); x absmax partials on 18..1041 =====
__global__ __launch_bounds__(256) void k_absmax_qw(const float* __restrict__ x,
                                                   const float* __restrict__ w1,
                                                   const float* __restrict__ w2,
                                                   char* __restrict__ qw1, char* __restrict__ qw2,
                                                   int* __restrict__ wb1, int* __restrict__ wb2,
                                                   int* __restrict__ wsum, float* __restrict__ scal,
                                                   float* __restrict__ wsred) {
    __shared__ union { float red[256]; int wsl[256]; } sm;
    int b = blockIdx.x, t = threadIdx.x;
    if (b >= 18) {                        // x absmax -> per-block partial, plain store
        int xb = b - 18;
        float mx = 0.f;
        const float4* p4 = (const float4*)x;
        for (int i = xb * 256 + t; i < 802816; i += 1024 * 256) {
            float4 v = p4[i];
            mx = fmaxf(mx, fmaxf(fmaxf(fabsf(v.x), fabsf(v.y)),
                                 fmaxf(fabsf(v.z), fabsf(v.w))));
        }
        mx = block_redmax(mx, sm.red, t);
        if (t == 0) wsred[xb] = mx;
        return;
    }
    // 18 blocks: (wsel, kp). Block-local tensor absmax (coalesced 36KB read), then quantize slice.
    int wsel = b / 9, kp = b - wsel * 9;
    const float* w = wsel ? w2 : w1;
    char* qw = wsel ? qw2 : qw1;
    int* wb  = wsel ? wb2 : wb1;
    float mx = 0.f;
    const float4* p4 = (const float4*)w;
    for (int i = t; i < 9216; i += 256) {
        float4 v = p4[i];
        mx = fmaxf(mx, fmaxf(fmaxf(fabsf(v.x), fabsf(v.y)),
                             fmaxf(fabsf(v.z), fabsf(v.w))));
    }
    float maxW = block_redmax(mx, sm.red, t);
    if (t == 0 && kp == 0) scal[1 + wsel] = maxW;
    float s = maxW / 127.f;
    int co = t & 63, cg = t >> 6, ci0 = cg * 16;
    signed char qv[16];
    int qsum = 0;
#pragma unroll
    for (int i = 0; i < 16; i++) {
        int ci = ci0 + i;
        float v = w[((size_t)co * 64 + ci) * 9 + kp];
        float qf = rintf(v / s);
        qf = fminf(fmaxf(qf, -127.f), 127.f);
        int q = (int)qf;
        qv[i] = (signed char)q;
        qsum += q;
    }
    u32 pk[4];
#pragma unroll
    for (int d = 0; d < 4; d++)
        pk[d] = ((u32)(unsigned char)qv[d*4]) | ((u32)(unsigned char)qv[d*4+1] << 8)
              | ((u32)(unsigned char)qv[d*4+2] << 16) | ((u32)(unsigned char)qv[d*4+3] << 24);
    *(uint4*)&qw[(size_t)(kp * 64 + co) * 64 + ci0] = *(uint4*)pk;
#pragma unroll
    for (int i = 0; i < 16; i++) {
        u32 uu = (u32)(unsigned char)qv[i];
#pragma unroll
        for (int k = 0; k < 8; k++) {
            unsigned long long bal = __ballot((uu >> k) & 1);
            if (co == 0) wb[((ci0 + i) * 8 + k) * 9 + kp] = __popcll(bal);
        }
    }
    if (wsel == 1) {
        __syncthreads();
        sm.wsl[t] = qsum; __syncthreads();
        if (t < 64)
            atomicAdd(&wsum[t], sm.wsl[t] + sm.wsl[t + 64] + sm.wsl[t + 128] + sm.wsl[t + 192]);
    }
}

// ===== K2: quantize x -> padded NHWC int8; pad blocks exit early; (0,1) publishes scal[0] =====
__global__ __launch_bounds__(256) void k_quant_x(const float* __restrict__ x,
                                                 char* __restrict__ qpad,
                                                 const float* __restrict__ wsred,
                                                 float* __restrict__ scal) {
    __shared__ union { float red[256]; char lq[4096]; } sm;
    int n = blockIdx.x, yy = blockIdx.y, t = threadIdx.x;
    u32* row = (u32*)(qpad + (size_t)(1 + n * ROWS_PI + yy) * PADROW);
    if (n == 0 && yy == 0) {              // global leading zero row
        u32* r0 = (u32*)qpad;
        for (int j = t; j < 1024; j += 256) r0[j] = 0u;
    }
    if (yy == 0 || yy == 57) {
        for (int j = t; j < 1024; j += 256) row[j] = 0u;
        return;
    }
    // reduce the 1024 absmax partials locally (parallel, L2-broadcast)
    float a = fmaxf(fmaxf(wsred[t], wsred[t + 256]),
                    fmaxf(wsred[t + 512], wsred[t + 768]));
    float maxX = block_redmax(a, sm.red, t);
    if (n == 0 && yy == 1 && t == 0) scal[0] = maxX;
    int y = yy - 1;
    float sxq = maxX / 127.f;
    const float4* xr = (const float4*)(x + (size_t)n * 200704 + (size_t)y * 56);
    for (int j = t; j < 896; j += 256) {   // 64 ch x 14 float4
        int c = j / 14, xq = j - c * 14;
        float4 v = xr[(size_t)c * 784 + xq];
#pragma unroll
        for (int i = 0; i < 4; i++) {
            float q = rintf(((const float*)&v)[i] / sxq);
            q = fminf(fmaxf(q, -127.f), 127.f);
            sm.lq[(4 * xq + i) * 64 + c] = (char)(int)q;
        }
    }
    __syncthreads();
    u32* lqd = (u32*)sm.lq;
    for (int j = t; j < 1024; j += 256) row[j] = (j < 896) ? lqd[j] : 0u;
}

// ===== bit-stats (stride-9 conflict-free reduce) =====
static __device__ __forceinline__ void unpack_acc(u32 v, u32 pk[8]) {
#pragma unroll
    for (int k = 0; k < 8; k++) pk[k] += (v >> k) & 0x01010101u;
}

static __device__ __forceinline__ void reduce_cat(u32* red, int* gdst, const u32 pk[8],
                                                  bool active, int t) {
#pragma unroll
    for (int k = 0; k < 8; k++) red[t * 9 + k] = active ? pk[k] : 0u;
    __syncthreads();
#pragma unroll
    for (int p = t; p < 512; p += 256) {
        int ci = p >> 3, k = p & 7, ci4 = ci >> 2, bb = ci & 3;
        int sum = 0;
#pragma unroll
        for (int xo = 0; xo < 16; xo++)
            sum += (red[(xo * 16 + ci4) * 9 + k] >> (8 * bb)) & 0xFF;
        if (sum) atomicAdd(&gdst[p], sum);
    }
    __syncthreads();
}

// packed u32 of 4 channel bits for (row, xx, ci4): FROMF recomputes quant from float o-row
// (bit-exact with k_qrelu1's stored q1: same fmaxf/rintf/fminf sequence, same s1).
template <int FROMF>
static __device__ __forceinline__ u32 pk_at(const u32* img, const float* ofb, float s1,
                                            u32 xm, int row, int xx, int ci4) {
    if (FROMF) {
        float4 v = *(const float4*)(ofb + (size_t)row * 3584 + xx * 64 + ci4 * 4);
        u32 pk = 0;
#pragma unroll
        for (int i = 0; i < 4; i++) {
            float vv = fmaxf(((const float*)&v)[i], 0.f);
            u32 q = (u32)(int)fminf(rintf(vv / s1), 255.f);
            pk |= q << (8 * i);
        }
        return pk;
    }
    return img[(size_t)row * 1024 + xx * 16 + ci4] ^ xm;
}

// 128 seven-row units: s -> (n = s/8, slab = s%8), rows y0=slab*7..+6
template <int FROMF>
static __device__ void stats_unit(u32* red, const char* qpad, const float* of, float s1,
                                  u32 xorm, int* gst, int s, int t) {
    int n = s >> 3, slab = s & 7;
    int ci4 = t & 15, xo = t >> 4;
    const u32* img = FROMF ? nullptr : (const u32*)(qpad + (size_t)(2 + n * ROWS_PI) * PADROW);
    const float* ofb = FROMF ? (of + (size_t)n * 56 * 3584) : nullptr;
    u32 xm = xorm * 0x01010101u;
    int y0 = slab * 7;
    {   // main total (j=0)
        u32 pk[8] = {0,0,0,0,0,0,0,0};
#pragma unroll
        for (int r = 0; r < 7; r++)
#pragma unroll
            for (int j = 0; j < 4; j++) {
                int xx = xo + 16 * j;
                if (xx < 56) unpack_acc(pk_at<FROMF>(img, ofb, s1, xm, y0 + r, xx, ci4), pk);
            }
        reduce_cat(red, gst + 0 * 512, pk, true, t);
    }
    {   // Cleft (j=3)
        u32 pk[8] = {0,0,0,0,0,0,0,0};
        bool act = (xo == 0);
        if (act)
#pragma unroll
            for (int r = 0; r < 7; r++)
                unpack_acc(pk_at<FROMF>(img, ofb, s1, xm, y0 + r, 0, ci4), pk);
        reduce_cat(red, gst + 3 * 512, pk, act, t);
    }
    {   // Cright (j=4)
        u32 pk[8] = {0,0,0,0,0,0,0,0};
        bool act = (xo == 7);
        if (act)
#pragma unroll
            for (int r = 0; r < 7; r++)
                unpack_acc(pk_at<FROMF>(img, ofb, s1, xm, y0 + r, 55, ci4), pk);
        reduce_cat(red, gst + 4 * 512, pk, act, t);
    }
    if (slab == 0) {   // Rtop (j=1) + corners 5,6
        u32 pk[8] = {0,0,0,0,0,0,0,0};
#pragma unroll
        for (int j = 0; j < 4; j++) {
            int xx = xo + 16 * j;
            if (xx < 56) unpack_acc(pk_at<FROMF>(img, ofb, s1, xm, 0, xx, ci4), pk);
        }
        reduce_cat(red, gst + 1 * 512, pk, true, t);
        if (t < 32) {
            int which = t >> 4, c4 = t & 15;
            u32 v = pk_at<FROMF>(img, ofb, s1, xm, 0, which ? 55 : 0, c4);
            for (int b = 0; b < 4; b++)
                for (int k = 0; k < 8; k++)
                    if ((v >> (8 * b + k)) & 1)
                        atomicAdd(&gst[(5 + which) * 512 + (c4 * 4 + b) * 8 + k], 1);
        }
    }
    if (slab == 7) {   // Rbot (j=2) + corners 7,8
        u32 pk[8] = {0,0,0,0,0,0,0,0};
#pragma unroll
        for (int j = 0; j < 4; j++) {
            int xx = xo + 16 * j;
            if (xx < 56) unpack_acc(pk_at<FROMF>(img, ofb, s1, xm, 55, xx, ci4), pk);
        }
        reduce_cat(red, gst + 2 * 512, pk, true, t);
        if (t < 32) {
            int which = t >> 4, c4 = t & 15;
            u32 v = pk_at<FROMF>(img, ofb, s1, xm, 55, which ? 55 : 0, c4);
            for (int b = 0; b < 4; b++)
                for (int k = 0; k < 8; k++)
                    if ((v >> (8 * b + k)) & 1)
                        atomicAdd(&gst[(7 + which) * 512 + (c4 * 4 + b) * 8 + k], 1);
        }
    }
}

// ===== K3/K5: int8 3x3 conv via MFMA — zero-LDS streaming: A and B loaded straight
// from L2-resident global. Per wave, both A and B fragment loads cover contiguous 1KB
// spans (fully coalesced). No barriers in the main loop; occupancy VGPR-bound. =====
template <int SECOND>
__global__ __launch_bounds__(256, 2) void k_conv(const char* __restrict__ qin,
                                                 const char* __restrict__ qw,
                                                 const int* __restrict__ wsum,
                                                 const char* __restrict__ qid,
                                                 const float* __restrict__ gg, const float* __restrict__ bb,
                                                 const float* __restrict__ mmp, const float* __restrict__ vvp,
                                                 const float* __restrict__ scal,
                                                 float* __restrict__ outp, u32* __restrict__ rmaxp) {
    __shared__ float red[4];
    int b = blockIdx.x, t = threadIdx.x;
    int w = t >> 6, lane = t & 63, mq = lane & 15, quad = lane >> 4;
    int u0 = b * 2;                            // rows u0, u0+1 (same image: 56 even)
    int n = u0 / 56, y = u0 - n * 56;
    const v4i* qin4 = (const v4i*)qin;         // 16B units; PADROW = 256 uint4
    size_t rbase = (size_t)(1 + n * ROWS_PI + y) * 256;
    v4i acc[2][4] = {{{0,0,0,0},{0,0,0,0},{0,0,0,0},{0,0,0,0}},
                     {{0,0,0,0},{0,0,0,0},{0,0,0,0},{0,0,0,0}}};
#pragma unroll
    for (int tap = 0; tap < 9; tap++) {
        const int ky = tap / 3, kx = tap - ky * 3;
        v4i bf[4];
#pragma unroll
        for (int nt = 0; nt < 4; nt++)
            bf[nt] = *(const v4i*)&qw[(size_t)((tap * 64 + nt * 16 + mq) << 6) + quad * 16];
        int px = w * 16 + mq + kx;             // input pixel x = px-1 (px=65 feeds only discarded col 63)
#pragma unroll
        for (int rr = 0; rr < 2; rr++) {
            v4i a = qin4[rbase + (size_t)(rr + ky) * 256 - 4 + px * 4 + quad];
#pragma unroll
            for (int nt = 0; nt < 4; nt++)
                acc[rr][nt] = __builtin_amdgcn_mfma_i32_16x16x64_i8(a, bf[nt], acc[rr][nt], 0, 0, 0);
        }
    }
    // epilogue
    float sIn = SECOND ? __uint_as_float(((const u32*)scal)[32]) / 255.f : scal[0] / 127.f;
    float sW  = scal[1 + SECOND] / 127.f;
    float sx  = scal[0] / 127.f;
    float alpha[4], beta[4]; int wofs[4];
#pragma unroll
    for (int nt = 0; nt < 4; nt++) {
        int co = nt * 16 + mq;
        float inv = gg[co] * rsqrtf(vvp[co] + 1e-5f);
        alpha[nt] = sIn * sW * inv;
        beta[nt]  = bb[co] - mmp[co] * inv;
        wofs[nt]  = SECOND ? (wsum[co] << 7) : 0;
    }
    float lmax = 0.f;
#pragma unroll
    for (int rr = 0; rr < 2; rr++) {
        int uu = u0 + rr, yr = y + rr;
        size_t rowb = (size_t)uu * 3584;
        const signed char* idrow = SECOND
            ? (const signed char*)(qid + (size_t)(2 + n * ROWS_PI + yr) * PADROW) : nullptr;
#pragma unroll
        for (int nt = 0; nt < 4; nt++) {
            int co = nt * 16 + mq;
#pragma unroll
            for (int r = 0; r < 4; r++) {
                int xx = w * 16 + quad * 4 + r;
                if (xx < 56) {
                    float o = (float)(acc[rr][nt][r] + wofs[nt]) * alpha[nt] + beta[nt];
                    if (SECOND) o += sx * (float)idrow[xx * 64 + co];
                    outp[rowb + xx * 64 + co] = o;
                    lmax = fmaxf(lmax, o);
                }
            }
        }
    }
    // wave-level max reduce, one atomic per block
#pragma unroll
    for (int off = 32; off > 0; off >>= 1) lmax = fmaxf(lmax, __shfl_down(lmax, off));
    if (lane == 0) red[w] = lmax;
    __syncthreads();
    if (t == 0)
        atomicMax(rmaxp, __float_as_uint(fmaxf(fmaxf(red[0], red[1]), fmaxf(red[2], red[3]))));
}

// ===== K4: quant_relu1 + stats(qx) + stats(q1 recomputed from o1) =====
__global__ __launch_bounds__(256) void k_qrelu1(const float* __restrict__ o1,
                                                char* __restrict__ q1,
                                                const char* __restrict__ qx,
                                                const float* __restrict__ scal,
                                                int* __restrict__ stx, int* __restrict__ stq) {
    __shared__ u32 sred[2304];
    int b = blockIdx.x, t = threadIdx.x;
    if (b >= 1056) {   // stats(q1) from o1 + s1 (bit-exact recompute)
        float s1 = __uint_as_float(((const u32*)scal)[32]) / 255.f;
        stats_unit<1>(sred, nullptr, o1, s1, 0u, stq, b - 1056, t);
        return;
    }
    if (b >= 928) { stats_unit<0>(sred, qx, nullptr, 0.f, 0u, stx, b - 928, t); return; }
    int n = b / 58, yy = b - n * 58;
    u32* row = (u32*)(q1 + (size_t)(1 + n * ROWS_PI + yy) * PADROW);
    if (n == 0 && yy == 0) {
        u32* r0 = (u32*)q1;
        for (int j = t; j < 1024; j += 256) r0[j] = 0x80808080u;
    }
    if (yy == 0 || yy == 57) {
        for (int j = t; j < 1024; j += 256) row[j] = 0x80808080u;
        return;
    }
    int y = yy - 1;
    float s1 = __uint_as_float(((const u32*)scal)[32]) / 255.f;
    const float4* o4 = (const float4*)(o1 + (size_t)(n * 56 + y) * 3584);
    for (int j = t; j < 1024; j += 256) {
        u32 pk = 0x80808080u;
        if (j < 896) {
            float4 v = o4[j];
            pk = 0u;
#pragma unroll
            for (int i = 0; i < 4; i++) {
                float vv = fmaxf(((const float*)&v)[i], 0.f);
                float q = fminf(rintf(vv / s1), 255.f);
                pk |= ((u32)(unsigned char)(char)((int)q - 128)) << (8 * i);
            }
        }
        row[j] = pk;
    }
}

// ===== K6: final quantize + NHWC->NCHW (2 rows/block) + HM tail block =====
__global__ __launch_bounds__(256) void k_final(const float* __restrict__ o2,
                                               const float* __restrict__ scal,
                                               float* __restrict__ outp,
                                               const int* __restrict__ stx, const int* __restrict__ stq,
                                               const int* __restrict__ wb1, const int* __restrict__ wb2) {
    __shared__ union { float lt[64 * 57]; long long r1[256]; } sm;
    int b = blockIdx.x, t = threadIdx.x;
    if (b == 448) {    // HM combine (stx/stq complete since k_qrelu1)
        long long act = 0, en = 0;
#pragma unroll
        for (int half = 0; half < 2; half++) {
            int tt = t + half * 256;   // tt = ci*8 + k
#pragma unroll
            for (int wsel = 0; wsel < 2; wsel++) {
                const int* st = wsel ? stq : stx;
                const int* wb = wsel ? wb2 : wb1;
                long long s[9];
#pragma unroll
                for (int j = 0; j < 9; j++) s[j] = st[j * 512 + tt];
                int wr[9];
#pragma unroll
                for (int j = 0; j < 9; j++) wr[j] = wb[tt * 9 + j];
                long long wall = 0;
#pragma unroll
                for (int j = 0; j < 9; j++) wall += wr[j];
                long long wr0 = (long long)wr[0] + wr[1] + wr[2];
                long long wr2 = (long long)wr[6] + wr[7] + wr[8];
                long long wc0 = (long long)wr[0] + wr[3] + wr[6];
                long long wc2 = (long long)wr[2] + wr[5] + wr[8];
                en += s[0] * wall - s[1] * wr2 - s[2] * wr0 - s[3] * wc2 - s[4] * wc0
                    + s[5] * (long long)wr[8] + s[6] * (long long)wr[6]
                    + s[7] * (long long)wr[2] + s[8] * (long long)wr[0];
                act += s[0];
            }
        }
        sm.r1[t] = en; __syncthreads();
        for (int s = 128; s > 0; s >>= 1) { if (t < s) sm.r1[t] += sm.r1[t + s]; __syncthreads(); }
        long long etot = sm.r1[0]; __syncthreads();
        sm.r1[t] = act; __syncthreads();
        for (int s = 128; s > 0; s >>= 1) { if (t < s) sm.r1[t] += sm.r1[t + s]; __syncthreads(); }
        if (t == 0) {
            outp[OUTN]     = (float)sm.r1[0];   // HM_act
            outp[OUTN + 1] = (float)etot;       // HM_energy
        }
        return;
    }
    float s2 = __uint_as_float(((const u32*)scal)[64]) / 255.f;
#pragma unroll
    for (int rr = 0; rr < 2; rr++) {
        int u = b * 2 + rr;
        int n = u / 56, y = u - n * 56;
        __syncthreads();
        const float4* o4 = (const float4*)(o2 + (size_t)u * 3584);
        for (int j = t; j < 896; j += 256) {      // 56 xx x 16 c4-groups
            int xx = j >> 4, c4 = j & 15;
            float4 v = o4[j];
#pragma unroll
            for (int i = 0; i < 4; i++) {
                float vv = fmaxf(((const float*)&v)[i], 0.f);
                float q = fminf(rintf(vv / s2), 255.f);
                sm.lt[(4 * c4 + i) * 57 + xx] = q * s2;
            }
        }
        __syncthreads();
        for (int idx = t; idx < 3584; idx += 256) {
            int co = idx / 56, xx = idx - co * 56;
            outp[(size_t)n * 200704 + (size_t)co * 3136 + y * 56 + xx] = sm.lt[co * 57 + xx];
        }
    }
}

extern "C" void kernel_launch(void* const* d_in, const int* in_sizes, int n_in,
                              void* d_out, int out_size, void* d_ws, size_t ws_size,
                              hipStream_t stream) {
    if (ws_size < WS_NEED) return;
    const float* x  = (const float*)d_in[0];
    const float* w1 = (const float*)d_in[1];
    const float* w2 = (const float*)d_in[2];
    const float* g1 = (const float*)d_in[3];
    const float* b1 = (const float*)d_in[4];
    const float* m1 = (const float*)d_in[5];
    const float* v1 = (const float*)d_in[6];
    const float* g2 = (const float*)d_in[7];
    const float* b2 = (const float*)d_in[8];
    const float* m2 = (const float*)d_in[9];
    const float* v2 = (const float*)d_in[10];
    char* ws = (char*)d_ws;
    char* qx  = ws + OFS_QX;
    char* q1  = ws + OFS_Q1;
    float* o1 = (float*)(ws + OFS_O1);
    float* o2 = (float*)(ws + OFS_O2);
    char* qw1 = ws + OFS_QW1;
    char* qw2 = ws + OFS_QW2;
    int* wb1  = (int*)(ws + OFS_WB1);
    int* wb2  = (int*)(ws + OFS_WB2);
    int* wsum = (int*)(ws + OFS_WSUM);
    float* scal = (float*)(ws + OFS_SCAL);
    u32* rmax1 = (u32*)(ws + OFS_SCAL + 128);
    u32* rmax2 = (u32*)(ws + OFS_SCAL + 256);
    int* stx  = (int*)(ws + OFS_STX);
    int* stq  = (int*)(ws + OFS_STQ);
    float* wsred = (float*)(ws + OFS_WSRED);
    float* outp = (float*)d_out;

    (void)hipMemsetAsync(ws + OFS_WSUM, 0, ZSPAN, stream);
    k_absmax_qw<<<1042, 256, 0, stream>>>(x, w1, w2, qw1, qw2, wb1, wb2, wsum, scal, wsred);
    k_quant_x<<<dim3(16, 58), 256, 0, stream>>>(x, qx, wsred, scal);
    k_conv<0><<<448, 256, 0, stream>>>(qx, qw1, wsum, nullptr,
                                       g1, b1, m1, v1, scal, o1, rmax1);
    k_qrelu1<<<1184, 256, 0, stream>>>(o1, q1, qx, scal, stx, stq);
    k_conv<1><<<448, 256, 0, stream>>>(q1, qw2, wsum, qx,
                                       g2, b2, m2, v2, scal, o2, rmax2);
    k_final<<<449, 256, 0, stream>>>(o2, scal, outp, stx, stq, wb1, wb2);
}

// Round 11
// 169.036 us; speedup vs baseline: 1.0418x; 1.0418x over previous
//
#include <hip/hip_runtime.h>

using u32 = unsigned int;
typedef int v4i __attribute__((ext_vector_type(4)));

// ===== geometry =====
constexpr int N_IMG   = 16;
constexpr int PADROW  = 4096;   // 64 px * 64 ch bytes
constexpr int ROWS_PI = 58;     // 56 real + top/bottom pad

// ===== workspace layout (bytes) =====
constexpr size_t OFS_QX   = 4096;
constexpr size_t SZ_QPAD  = (size_t)(1 + N_IMG * ROWS_PI) * PADROW;
constexpr size_t OFS_Q1   = OFS_QX + SZ_QPAD;
constexpr size_t OFS_O1   = OFS_Q1 + SZ_QPAD;
constexpr size_t SZ_OF    = (size_t)N_IMG * 56 * 56 * 64 * 4;
constexpr size_t OFS_O2   = OFS_O1 + SZ_OF;
constexpr size_t OFS_QW1  = OFS_O2 + SZ_OF;
constexpr size_t OFS_QW2  = OFS_QW1 + 36864;
constexpr size_t OFS_WB1  = OFS_QW2 + 36864;
constexpr size_t OFS_WB2  = OFS_WB1 + 18432;
constexpr size_t OFS_WSUM = OFS_WB2 + 18432;      // wsum9[9][64] ints, plain stores (no zero needed)
constexpr size_t OFS_SCAL = OFS_WSUM + 2304;      // maxX/maxW1/maxW2 @0; rmax1 @+128; rmax2 @+256
constexpr size_t OFS_STX  = OFS_SCAL + 384;       // 4608 ints (zeroed by K1 block 18)
constexpr size_t OFS_STQ  = OFS_STX + 18432;      // 4608 ints (zeroed by K1 block 19)
constexpr size_t OFS_WSRED= OFS_STQ + 18432;      // 1024 floats absmax partials (all overwritten)
constexpr size_t WS_NEED  = OFS_WSRED + 4096;
constexpr size_t OUTN     = (size_t)16 * 64 * 56 * 56;

// ===== helpers =====
static __device__ __forceinline__ float block_redmax(float v, float* red, int t) {
    red[t] = v; __syncthreads();
    for (int s = 128; s > 0; s >>= 1) {
        if (t < s) red[t] = fmaxf(red[t], red[t + s]);
        __syncthreads();
    }
    float r = red[0]; __syncthreads();
    return r;
}

// ===== K1: weight quant (blocks 0..17) + x absmax partials (18..1041) + accumulator zeroing =====
__global__ __launch_bounds__(256) void k_absmax_qw(const float* __restrict__ x,
                                                   const float* __restrict__ w1,
                                                   const float* __restrict__ w2,
                                                   char* __restrict__ qw1, char* __restrict__ qw2,
                                                   int* __restrict__ wb1, int* __restrict__ wb2,
                                                   int* __restrict__ wsum9, float* __restrict__ scal,
                                                   float* __restrict__ wsred,
                                                   int* __restrict__ stx, int* __restrict__ stq) {
    __shared__ union { float red[256]; int wsl[256]; } sm;
    int b = blockIdx.x, t = threadIdx.x;
    if (b >= 18) {                        // x absmax -> per-block partial, plain store
        int xb = b - 18;
        // fold the old memset dispatch into spare capacity of three blocks
        if (b == 18) for (int i = t; i < 4608; i += 256) stx[i] = 0;
        if (b == 19) for (int i = t; i < 4608; i += 256) stq[i] = 0;
        if (b == 20 && t == 0) { ((u32*)scal)[32] = 0u; ((u32*)scal)[64] = 0u; }  // rmax1/rmax2
        float mx = 0.f;
        const float4* p4 = (const float4*)x;
        for (int i = xb * 256 + t; i < 802816; i += 1024 * 256) {
            float4 v = p4[i];
            mx = fmaxf(mx, fmaxf(fmaxf(fabsf(v.x), fabsf(v.y)),
                                 fmaxf(fabsf(v.z), fabsf(v.w))));
        }
        mx = block_redmax(mx, sm.red, t);
        if (t == 0) wsred[xb] = mx;
        return;
    }
    // 18 blocks: (wsel, kp). Block-local tensor absmax (coalesced 36KB read), then quantize slice.
    int wsel = b / 9, kp = b - wsel * 9;
    const float* w = wsel ? w2 : w1;
    char* qw = wsel ? qw2 : qw1;
    int* wb  = wsel ? wb2 : wb1;
    float mx = 0.f;
    const float4* p4 = (const float4*)w;
    for (int i = t; i < 9216; i += 256) {
        float4 v = p4[i];
        mx = fmaxf(mx, fmaxf(fmaxf(fabsf(v.x), fabsf(v.y)),
                             fmaxf(fabsf(v.z), fabsf(v.w))));
    }
    float maxW = block_redmax(mx, sm.red, t);
    if (t == 0 && kp == 0) scal[1 + wsel] = maxW;
    float s = maxW / 127.f;
    int co = t & 63, cg = t >> 6, ci0 = cg * 16;
    signed char qv[16];
    int qsum = 0;
#pragma unroll
    for (int i = 0; i < 16; i++) {
        int ci = ci0 + i;
        float v = w[((size_t)co * 64 + ci) * 9 + kp];
        float qf = rintf(v / s);
        qf = fminf(fmaxf(qf, -127.f), 127.f);
        int q = (int)qf;
        qv[i] = (signed char)q;
        qsum += q;
    }
    u32 pk[4];
#pragma unroll
    for (int d = 0; d < 4; d++)
        pk[d] = ((u32)(unsigned char)qv[d*4]) | ((u32)(unsigned char)qv[d*4+1] << 8)
              | ((u32)(unsigned char)qv[d*4+2] << 16) | ((u32)(unsigned char)qv[d*4+3] << 24);
    *(uint4*)&qw[(size_t)(kp * 64 + co) * 64 + ci0] = *(uint4*)pk;
#pragma unroll
    for (int i = 0; i < 16; i++) {
        u32 uu = (u32)(unsigned char)qv[i];
#pragma unroll
        for (int k = 0; k < 8; k++) {
            unsigned long long bal = __ballot((uu >> k) & 1);
            if (co == 0) wb[((ci0 + i) * 8 + k) * 9 + kp] = __popcll(bal);
        }
    }
    if (wsel == 1) {   // per-kp partial sums, plain stores (summed by conv2)
        __syncthreads();
        sm.wsl[t] = qsum; __syncthreads();
        if (t < 64)
            wsum9[kp * 64 + t] = sm.wsl[t] + sm.wsl[t + 64] + sm.wsl[t + 128] + sm.wsl[t + 192];
    }
}

// ===== K2: quantize x -> padded NHWC int8; pad blocks exit early; (0,1) publishes scal[0] =====
__global__ __launch_bounds__(256) void k_quant_x(const float* __restrict__ x,
                                                 char* __restrict__ qpad,
                                                 const float* __restrict__ wsred,
                                                 float* __restrict__ scal) {
    __shared__ union { float red[256]; char lq[4096]; } sm;
    int n = blockIdx.x, yy = blockIdx.y, t = threadIdx.x;
    u32* row = (u32*)(qpad + (size_t)(1 + n * ROWS_PI + yy) * PADROW);
    if (n == 0 && yy == 0) {              // global leading zero row
        u32* r0 = (u32*)qpad;
        for (int j = t; j < 1024; j += 256) r0[j] = 0u;
    }
    if (yy == 0 || yy == 57) {
        for (int j = t; j < 1024; j += 256) row[j] = 0u;
        return;
    }
    // reduce the 1024 absmax partials locally (parallel, L2-broadcast)
    float a = fmaxf(fmaxf(wsred[t], wsred[t + 256]),
                    fmaxf(wsred[t + 512], wsred[t + 768]));
    float maxX = block_redmax(a, sm.red, t);
    if (n == 0 && yy == 1 && t == 0) scal[0] = maxX;
    int y = yy - 1;
    float sxq = maxX / 127.f;
    const float4* xr = (const float4*)(x + (size_t)n * 200704 + (size_t)y * 56);
    for (int j = t; j < 896; j += 256) {   // 64 ch x 14 float4
        int c = j / 14, xq = j - c * 14;
        float4 v = xr[(size_t)c * 784 + xq];
#pragma unroll
        for (int i = 0; i < 4; i++) {
            float q = rintf(((const float*)&v)[i] / sxq);
            q = fminf(fmaxf(q, -127.f), 127.f);
            sm.lq[(4 * xq + i) * 64 + c] = (char)(int)q;
        }
    }
    __syncthreads();
    u32* lqd = (u32*)sm.lq;
    for (int j = t; j < 1024; j += 256) row[j] = (j < 896) ? lqd[j] : 0u;
}

// ===== bit-stats (stride-9 conflict-free reduce) =====
static __device__ __forceinline__ void unpack_acc(u32 v, u32 pk[8]) {
#pragma unroll
    for (int k = 0; k < 8; k++) pk[k] += (v >> k) & 0x01010101u;
}

static __device__ __forceinline__ void reduce_cat(u32* red, int* gdst, const u32 pk[8],
                                                  bool active, int t) {
#pragma unroll
    for (int k = 0; k < 8; k++) red[t * 9 + k] = active ? pk[k] : 0u;
    __syncthreads();
#pragma unroll
    for (int p = t; p < 512; p += 256) {
        int ci = p >> 3, k = p & 7, ci4 = ci >> 2, bb = ci & 3;
        int sum = 0;
#pragma unroll
        for (int xo = 0; xo < 16; xo++)
            sum += (red[(xo * 16 + ci4) * 9 + k] >> (8 * bb)) & 0xFF;
        if (sum) atomicAdd(&gdst[p], sum);
    }
    __syncthreads();
}

// 128 seven-row units: s -> (n = s/8, slab = s%8), rows y0=slab*7..+6
static __device__ void stats_unit(u32* red, const char* qpad, u32 xorm, int* gst, int s, int t) {
    int n = s >> 3, slab = s & 7;
    int ci4 = t & 15, xo = t >> 4;
    const u32* img = (const u32*)(qpad + (size_t)(2 + n * ROWS_PI) * PADROW);
    u32 xm = xorm * 0x01010101u;
    int y0 = slab * 7;
    {   // main total (j=0)
        u32 pk[8] = {0,0,0,0,0,0,0,0};
#pragma unroll
        for (int r = 0; r < 7; r++) {
            const u32* row = img + (size_t)(y0 + r) * 1024;
#pragma unroll
            for (int j = 0; j < 4; j++) {
                int xx = xo + 16 * j;
                if (xx < 56) unpack_acc(row[xx * 16 + ci4] ^ xm, pk);
            }
        }
        reduce_cat(red, gst + 0 * 512, pk, true, t);
    }
    {   // Cleft (j=3)
        u32 pk[8] = {0,0,0,0,0,0,0,0};
        bool act = (xo == 0);
        if (act)
#pragma unroll
            for (int r = 0; r < 7; r++)
                unpack_acc(img[(size_t)(y0 + r) * 1024 + ci4] ^ xm, pk);
        reduce_cat(red, gst + 3 * 512, pk, act, t);
    }
    {   // Cright (j=4)
        u32 pk[8] = {0,0,0,0,0,0,0,0};
        bool act = (xo == 7);
        if (act)
#pragma unroll
            for (int r = 0; r < 7; r++)
                unpack_acc(img[(size_t)(y0 + r) * 1024 + 55 * 16 + ci4] ^ xm, pk);
        reduce_cat(red, gst + 4 * 512, pk, act, t);
    }
    if (slab == 0) {   // Rtop (j=1) + corners 5,6
        u32 pk[8] = {0,0,0,0,0,0,0,0};
#pragma unroll
        for (int j = 0; j < 4; j++) {
            int xx = xo + 16 * j;
            if (xx < 56) unpack_acc(img[xx * 16 + ci4] ^ xm, pk);
        }
        reduce_cat(red, gst + 1 * 512, pk, true, t);
        if (t < 32) {
            int which = t >> 4, c4 = t & 15;
            u32 v = img[(which ? 55 : 0) * 16 + c4] ^ xm;
            for (int b = 0; b < 4; b++)
                for (int k = 0; k < 8; k++)
                    if ((v >> (8 * b + k)) & 1)
                        atomicAdd(&gst[(5 + which) * 512 + (c4 * 4 + b) * 8 + k], 1);
        }
    }
    if (slab == 7) {   // Rbot (j=2) + corners 7,8
        u32 pk[8] = {0,0,0,0,0,0,0,0};
#pragma unroll
        for (int j = 0; j < 4; j++) {
            int xx = xo + 16 * j;
            if (xx < 56) unpack_acc(img[(size_t)55 * 1024 + xx * 16 + ci4] ^ xm, pk);
        }
        reduce_cat(red, gst + 2 * 512, pk, true, t);
        if (t < 32) {
            int which = t >> 4, c4 = t & 15;
            u32 v = img[(size_t)55 * 1024 + (which ? 55 : 0) * 16 + c4] ^ xm;
            for (int b = 0; b < 4; b++)
                for (int k = 0; k < 8; k++)
                    if ((v >> (8 * b + k)) & 1)
                        atomicAdd(&gst[(7 + which) * 512 + (c4 * 4 + b) * 8 + k], 1);
        }
    }
}

// ===== K3/K5: zero-LDS streaming int8 3x3 conv (blocks 0..447) + stats units (448..575).
// Stats read the SAME qin the conv reads (L2-hot). =====
template <int SECOND>
__global__ __launch_bounds__(256, 2) void k_conv(const char* __restrict__ qin,
                                                 const char* __restrict__ qw,
                                                 const int* __restrict__ wsum9,
                                                 const char* __restrict__ qid,
                                                 const float* __restrict__ gg, const float* __restrict__ bb,
                                                 const float* __restrict__ mmp, const float* __restrict__ vvp,
                                                 const float* __restrict__ scal,
                                                 float* __restrict__ outp, u32* __restrict__ rmaxp,
                                                 int* __restrict__ gst) {
    __shared__ union { float red[4]; u32 sred[2304]; } sm;
    int b = blockIdx.x, t = threadIdx.x;
    if (b >= 448) {    // bit-stats rider: qx for conv1 (xorm 0), q1 for conv2 (xorm 0x80)
        stats_unit(sm.sred, qin, SECOND ? 0x80u : 0u, gst, b - 448, t);
        return;
    }
    int w = t >> 6, lane = t & 63, mq = lane & 15, quad = lane >> 4;
    int u0 = b * 2;                            // rows u0, u0+1 (same image: 56 even)
    int n = u0 / 56, y = u0 - n * 56;
    const v4i* qin4 = (const v4i*)qin;         // 16B units; PADROW = 256 uint4
    size_t rbase = (size_t)(1 + n * ROWS_PI + y) * 256;
    v4i acc[2][4] = {{{0,0,0,0},{0,0,0,0},{0,0,0,0},{0,0,0,0}},
                     {{0,0,0,0},{0,0,0,0},{0,0,0,0},{0,0,0,0}}};
#pragma unroll
    for (int tap = 0; tap < 9; tap++) {
        const int ky = tap / 3, kx = tap - ky * 3;
        v4i bf[4];
#pragma unroll
        for (int nt = 0; nt < 4; nt++)
            bf[nt] = *(const v4i*)&qw[(size_t)((tap * 64 + nt * 16 + mq) << 6) + quad * 16];
        int px = w * 16 + mq + kx;             // input pixel x = px-1 (px=65 feeds only discarded col 63)
#pragma unroll
        for (int rr = 0; rr < 2; rr++) {
            v4i a = qin4[rbase + (size_t)(rr + ky) * 256 - 4 + px * 4 + quad];
#pragma unroll
            for (int nt = 0; nt < 4; nt++)
                acc[rr][nt] = __builtin_amdgcn_mfma_i32_16x16x64_i8(a, bf[nt], acc[rr][nt], 0, 0, 0);
        }
    }
    // epilogue
    float sIn = SECOND ? __uint_as_float(((const u32*)scal)[32]) / 255.f : scal[0] / 127.f;
    float sW  = scal[1 + SECOND] / 127.f;
    float sx  = scal[0] / 127.f;
    float alpha[4], beta[4]; int wofs[4];
#pragma unroll
    for (int nt = 0; nt < 4; nt++) {
        int co = nt * 16 + mq;
        float inv = gg[co] * rsqrtf(vvp[co] + 1e-5f);
        alpha[nt] = sIn * sW * inv;
        beta[nt]  = bb[co] - mmp[co] * inv;
        int ws9 = 0;
        if (SECOND) {
#pragma unroll
            for (int kp = 0; kp < 9; kp++) ws9 += wsum9[kp * 64 + co];
        }
        wofs[nt] = SECOND ? (ws9 << 7) : 0;
    }
    float lmax = 0.f;
#pragma unroll
    for (int rr = 0; rr < 2; rr++) {
        int uu = u0 + rr, yr = y + rr;
        size_t rowb = (size_t)uu * 3584;
        const signed char* idrow = SECOND
            ? (const signed char*)(qid + (size_t)(2 + n * ROWS_PI + yr) * PADROW) : nullptr;
#pragma unroll
        for (int nt = 0; nt < 4; nt++) {
            int co = nt * 16 + mq;
#pragma unroll
            for (int r = 0; r < 4; r++) {
                int xx = w * 16 + quad * 4 + r;
                if (xx < 56) {
                    float o = (float)(acc[rr][nt][r] + wofs[nt]) * alpha[nt] + beta[nt];
                    if (SECOND) o += sx * (float)idrow[xx * 64 + co];
                    outp[rowb + xx * 64 + co] = o;
                    lmax = fmaxf(lmax, o);
                }
            }
        }
    }
    // wave-level max reduce, one atomic per block
#pragma unroll
    for (int off = 32; off > 0; off >>= 1) lmax = fmaxf(lmax, __shfl_down(lmax, off));
    if (lane == 0) sm.red[w] = lmax;
    __syncthreads();
    if (t == 0)
        atomicMax(rmaxp, __float_as_uint(fmaxf(fmaxf(sm.red[0], sm.red[1]),
                                               fmaxf(sm.red[2], sm.red[3]))));
}

// ===== K4: quant_relu1 (pure: 928 blocks, float4 read, packed u32 write) =====
__global__ __launch_bounds__(256) void k_qrelu1(const float* __restrict__ o1,
                                                char* __restrict__ q1,
                                                const float* __restrict__ scal) {
    int b = blockIdx.x, t = threadIdx.x;
    int n = b / 58, yy = b - n * 58;
    u32* row = (u32*)(q1 + (size_t)(1 + n * ROWS_PI + yy) * PADROW);
    if (n == 0 && yy == 0) {
        u32* r0 = (u32*)q1;
        for (int j = t; j < 1024; j += 256) r0[j] = 0x80808080u;
    }
    if (yy == 0 || yy == 57) {
        for (int j = t; j < 1024; j += 256) row[j] = 0x80808080u;
        return;
    }
    int y = yy - 1;
    float s1 = __uint_as_float(((const u32*)scal)[32]) / 255.f;
    const float4* o4 = (const float4*)(o1 + (size_t)(n * 56 + y) * 3584);
    for (int j = t; j < 1024; j += 256) {
        u32 pk = 0x80808080u;
        if (j < 896) {
            float4 v = o4[j];
            pk = 0u;
#pragma unroll
            for (int i = 0; i < 4; i++) {
                float vv = fmaxf(((const float*)&v)[i], 0.f);
                float q = fminf(rintf(vv / s1), 255.f);
                pk |= ((u32)(unsigned char)(char)((int)q - 128)) << (8 * i);
            }
        }
        row[j] = pk;
    }
}

// ===== K6: final quantize + NHWC->NCHW (2 rows/block) + HM tail block =====
__global__ __launch_bounds__(256) void k_final(const float* __restrict__ o2,
                                               const float* __restrict__ scal,
                                               float* __restrict__ outp,
                                               const int* __restrict__ stx, const int* __restrict__ stq,
                                               const int* __restrict__ wb1, const int* __restrict__ wb2) {
    __shared__ union { float lt[64 * 57]; long long r1[256]; } sm;
    int b = blockIdx.x, t = threadIdx.x;
    if (b == 448) {    // HM combine (stx complete after conv1 dispatch, stq after conv2)
        long long act = 0, en = 0;
#pragma unroll
        for (int half = 0; half < 2; half++) {
            int tt = t + half * 256;   // tt = ci*8 + k
#pragma unroll
            for (int wsel = 0; wsel < 2; wsel++) {
                const int* st = wsel ? stq : stx;
                const int* wb = wsel ? wb2 : wb1;
                long long s[9];
#pragma unroll
                for (int j = 0; j < 9; j++) s[j] = st[j * 512 + tt];
                int wr[9];
#pragma unroll
                for (int j = 0; j < 9; j++) wr[j] = wb[tt * 9 + j];
                long long wall = 0;
#pragma unroll
                for (int j = 0; j < 9; j++) wall += wr[j];
                long long wr0 = (long long)wr[0] + wr[1] + wr[2];
                long long wr2 = (long long)wr[6] + wr[7] + wr[8];
                long long wc0 = (long long)wr[0] + wr[3] + wr[6];
                long long wc2 = (long long)wr[2] + wr[5] + wr[8];
                en += s[0] * wall - s[1] * wr2 - s[2] * wr0 - s[3] * wc2 - s[4] * wc0
                    + s[5] * (long long)wr[8] + s[6] * (long long)wr[6]
                    + s[7] * (long long)wr[2] + s[8] * (long long)wr[0];
                act += s[0];
            }
        }
        sm.r1[t] = en; __syncthreads();
        for (int s = 128; s > 0; s >>= 1) { if (t < s) sm.r1[t] += sm.r1[t + s]; __syncthreads(); }
        long long etot = sm.r1[0]; __syncthreads();
        sm.r1[t] = act; __syncthreads();
        for (int s = 128; s > 0; s >>= 1) { if (t < s) sm.r1[t] += sm.r1[t + s]; __syncthreads(); }
        if (t == 0) {
            outp[OUTN]     = (float)sm.r1[0];   // HM_act
            outp[OUTN + 1] = (float)etot;       // HM_energy
        }
        return;
    }
    float s2 = __uint_as_float(((const u32*)scal)[64]) / 255.f;
#pragma unroll
    for (int rr = 0; rr < 2; rr++) {
        int u = b * 2 + rr;
        int n = u / 56, y = u - n * 56;
        __syncthreads();
        const float4* o4 = (const float4*)(o2 + (size_t)u * 3584);
        for (int j = t; j < 896; j += 256) {      // 56 xx x 16 c4-groups
            int xx = j >> 4, c4 = j & 15;
            float4 v = o4[j];
#pragma unroll
            for (int i = 0; i < 4; i++) {
                float vv = fmaxf(((const float*)&v)[i], 0.f);
                float q = fminf(rintf(vv / s2), 255.f);
                sm.lt[(4 * c4 + i) * 57 + xx] = q * s2;
            }
        }
        __syncthreads();
        for (int idx = t; idx < 3584; idx += 256) {
            int co = idx / 56, xx = idx - co * 56;
            outp[(size_t)n * 200704 + (size_t)co * 3136 + y * 56 + xx] = sm.lt[co * 57 + xx];
        }
    }
}

extern "C" void kernel_launch(void* const* d_in, const int* in_sizes, int n_in,
                              void* d_out, int out_size, void* d_ws, size_t ws_size,
                              hipStream_t stream) {
    if (ws_size < WS_NEED) return;
    const float* x  = (const float*)d_in[0];
    const float* w1 = (const float*)d_in[1];
    const float* w2 = (const float*)d_in[2];
    const float* g1 = (const float*)d_in[3];
    const float* b1 = (const float*)d_in[4];
    const float* m1 = (const float*)d_in[5];
    const float* v1 = (const float*)d_in[6];
    const float* g2 = (const float*)d_in[7];
    const float* b2 = (const float*)d_in[8];
    const float* m2 = (const float*)d_in[9];
    const float* v2 = (const float*)d_in[10];
    char* ws = (char*)d_ws;
    char* qx  = ws + OFS_QX;
    char* q1  = ws + OFS_Q1;
    float* o1 = (float*)(ws + OFS_O1);
    float* o2 = (float*)(ws + OFS_O2);
    char* qw1 = ws + OFS_QW1;
    char* qw2 = ws + OFS_QW2;
    int* wb1  = (int*)(ws + OFS_WB1);
    int* wb2  = (int*)(ws + OFS_WB2);
    int* wsum9= (int*)(ws + OFS_WSUM);
    float* scal = (float*)(ws + OFS_SCAL);
    u32* rmax1 = (u32*)(ws + OFS_SCAL + 128);
    u32* rmax2 = (u32*)(ws + OFS_SCAL + 256);
    int* stx  = (int*)(ws + OFS_STX);
    int* stq  = (int*)(ws + OFS_STQ);
    float* wsred = (float*)(ws + OFS_WSRED);
    float* outp = (float*)d_out;

    k_absmax_qw<<<1042, 256, 0, stream>>>(x, w1, w2, qw1, qw2, wb1, wb2,
                                          wsum9, scal, wsred, stx, stq);
    k_quant_x<<<dim3(16, 58), 256, 0, stream>>>(x, qx, wsred, scal);
    k_conv<0><<<576, 256, 0, stream>>>(qx, qw1, wsum9, nullptr,
                                       g1, b1, m1, v1, scal, o1, rmax1, stx);
    k_qrelu1<<<928, 256, 0, stream>>>(o1, q1, scal);
    k_conv<1><<<576, 256, 0, stream>>>(q1, qw2, wsum9, qx,
                                       g2, b2, m2, v2, scal, o2, rmax2, stq);
    k_final<<<449, 256, 0, stream>>>(o2, scal, outp, stx, stq, wb1, wb2);
}

// Round 12
// 166.781 us; speedup vs baseline: 1.0559x; 1.0135x over previous
//
#include <hip/hip_runtime.h>

using u32 = unsigned int;
typedef int v4i __attribute__((ext_vector_type(4)));

// ===== geometry =====
constexpr int N_IMG   = 16;
constexpr int PADROW  = 4096;   // 64 px * 64 ch bytes
constexpr int ROWS_PI = 58;     // 56 real + top/bottom pad

// ===== workspace layout (bytes) =====
constexpr size_t OFS_QX   = 4096;
constexpr size_t SZ_QPAD  = (size_t)(1 + N_IMG * ROWS_PI) * PADROW;
constexpr size_t OFS_Q1   = OFS_QX + SZ_QPAD;          // (q1 slot retained, now unused)
constexpr size_t OFS_O1   = OFS_Q1 + SZ_QPAD;
constexpr size_t SZ_OF    = (size_t)N_IMG * 56 * 56 * 64 * 4;
constexpr size_t OFS_O2   = OFS_O1 + SZ_OF;
constexpr size_t OFS_QW1  = OFS_O2 + SZ_OF;
constexpr size_t OFS_QW2  = OFS_QW1 + 36864;
constexpr size_t OFS_WB1  = OFS_QW2 + 36864;
constexpr size_t OFS_WB2  = OFS_WB1 + 18432;
constexpr size_t OFS_WSUM = OFS_WB2 + 18432;      // wsum9[9][64] ints, plain stores
constexpr size_t OFS_SCAL = OFS_WSUM + 2304;      // maxX/maxW1/maxW2 @0; rmax1 @+128; rmax2 @+256
constexpr size_t OFS_STX  = OFS_SCAL + 384;       // 4608 ints (zeroed by K1 block 18)
constexpr size_t OFS_STQ  = OFS_STX + 18432;      // 4608 ints (zeroed by K1 block 19)
constexpr size_t OFS_WSRED= OFS_STQ + 18432;      // 1024 floats absmax partials (all overwritten)
constexpr size_t WS_NEED  = OFS_WSRED + 4096;
constexpr size_t OUTN     = (size_t)16 * 64 * 56 * 56;

// ===== helpers =====
static __device__ __forceinline__ float block_redmax(float v, float* red, int t) {
    red[t] = v; __syncthreads();
    for (int s = 128; s > 0; s >>= 1) {
        if (t < s) red[t] = fmaxf(red[t], red[t + s]);
        __syncthreads();
    }
    float r = red[0]; __syncthreads();
    return r;
}

// ===== K1: weight quant (blocks 0..17) + x absmax partials (18..1041) + accumulator zeroing =====
__global__ __launch_bounds__(256) void k_absmax_qw(const float* __restrict__ x,
                                                   const float* __restrict__ w1,
                                                   const float* __restrict__ w2,
                                                   char* __restrict__ qw1, char* __restrict__ qw2,
                                                   int* __restrict__ wb1, int* __restrict__ wb2,
                                                   int* __restrict__ wsum9, float* __restrict__ scal,
                                                   float* __restrict__ wsred,
                                                   int* __restrict__ stx, int* __restrict__ stq) {
    __shared__ union { float red[256]; int wsl[256]; } sm;
    int b = blockIdx.x, t = threadIdx.x;
    if (b >= 18) {                        // x absmax -> per-block partial, plain store
        int xb = b - 18;
        if (b == 18) for (int i = t; i < 4608; i += 256) stx[i] = 0;
        if (b == 19) for (int i = t; i < 4608; i += 256) stq[i] = 0;
        if (b == 20 && t == 0) { ((u32*)scal)[32] = 0u; ((u32*)scal)[64] = 0u; }  // rmax1/rmax2
        float mx = 0.f;
        const float4* p4 = (const float4*)x;
        for (int i = xb * 256 + t; i < 802816; i += 1024 * 256) {
            float4 v = p4[i];
            mx = fmaxf(mx, fmaxf(fmaxf(fabsf(v.x), fabsf(v.y)),
                                 fmaxf(fabsf(v.z), fabsf(v.w))));
        }
        mx = block_redmax(mx, sm.red, t);
        if (t == 0) wsred[xb] = mx;
        return;
    }
    // 18 blocks: (wsel, kp). Block-local tensor absmax (coalesced 36KB read), then quantize slice.
    int wsel = b / 9, kp = b - wsel * 9;
    const float* w = wsel ? w2 : w1;
    char* qw = wsel ? qw2 : qw1;
    int* wb  = wsel ? wb2 : wb1;
    float mx = 0.f;
    const float4* p4 = (const float4*)w;
    for (int i = t; i < 9216; i += 256) {
        float4 v = p4[i];
        mx = fmaxf(mx, fmaxf(fmaxf(fabsf(v.x), fabsf(v.y)),
                             fmaxf(fabsf(v.z), fabsf(v.w))));
    }
    float maxW = block_redmax(mx, sm.red, t);
    if (t == 0 && kp == 0) scal[1 + wsel] = maxW;
    float s = maxW / 127.f;
    int co = t & 63, cg = t >> 6, ci0 = cg * 16;
    signed char qv[16];
    int qsum = 0;
#pragma unroll
    for (int i = 0; i < 16; i++) {
        int ci = ci0 + i;
        float v = w[((size_t)co * 64 + ci) * 9 + kp];
        float qf = rintf(v / s);
        qf = fminf(fmaxf(qf, -127.f), 127.f);
        int q = (int)qf;
        qv[i] = (signed char)q;
        qsum += q;
    }
    u32 pk[4];
#pragma unroll
    for (int d = 0; d < 4; d++)
        pk[d] = ((u32)(unsigned char)qv[d*4]) | ((u32)(unsigned char)qv[d*4+1] << 8)
              | ((u32)(unsigned char)qv[d*4+2] << 16) | ((u32)(unsigned char)qv[d*4+3] << 24);
    *(uint4*)&qw[(size_t)(kp * 64 + co) * 64 + ci0] = *(uint4*)pk;
#pragma unroll
    for (int i = 0; i < 16; i++) {
        u32 uu = (u32)(unsigned char)qv[i];
#pragma unroll
        for (int k = 0; k < 8; k++) {
            unsigned long long bal = __ballot((uu >> k) & 1);
            if (co == 0) wb[((ci0 + i) * 8 + k) * 9 + kp] = __popcll(bal);
        }
    }
    if (wsel == 1) {   // per-kp partial sums, plain stores (summed by conv2)
        __syncthreads();
        sm.wsl[t] = qsum; __syncthreads();
        if (t < 64)
            wsum9[kp * 64 + t] = sm.wsl[t] + sm.wsl[t + 64] + sm.wsl[t + 128] + sm.wsl[t + 192];
    }
}

// ===== K2: quantize x -> padded NHWC int8; pad blocks exit early; (0,1) publishes scal[0] =====
__global__ __launch_bounds__(256) void k_quant_x(const float* __restrict__ x,
                                                 char* __restrict__ qpad,
                                                 const float* __restrict__ wsred,
                                                 float* __restrict__ scal) {
    __shared__ union { float red[256]; char lq[4096]; } sm;
    int n = blockIdx.x, yy = blockIdx.y, t = threadIdx.x;
    u32* row = (u32*)(qpad + (size_t)(1 + n * ROWS_PI + yy) * PADROW);
    if (n == 0 && yy == 0) {              // global leading zero row
        u32* r0 = (u32*)qpad;
        for (int j = t; j < 1024; j += 256) r0[j] = 0u;
    }
    if (yy == 0 || yy == 57) {
        for (int j = t; j < 1024; j += 256) row[j] = 0u;
        return;
    }
    float a = fmaxf(fmaxf(wsred[t], wsred[t + 256]),
                    fmaxf(wsred[t + 512], wsred[t + 768]));
    float maxX = block_redmax(a, sm.red, t);
    if (n == 0 && yy == 1 && t == 0) scal[0] = maxX;
    int y = yy - 1;
    float sxq = maxX / 127.f;
    const float4* xr = (const float4*)(x + (size_t)n * 200704 + (size_t)y * 56);
    for (int j = t; j < 896; j += 256) {   // 64 ch x 14 float4
        int c = j / 14, xq = j - c * 14;
        float4 v = xr[(size_t)c * 784 + xq];
#pragma unroll
        for (int i = 0; i < 4; i++) {
            float q = rintf(((const float*)&v)[i] / sxq);
            q = fminf(fmaxf(q, -127.f), 127.f);
            sm.lq[(4 * xq + i) * 64 + c] = (char)(int)q;
        }
    }
    __syncthreads();
    u32* lqd = (u32*)sm.lq;
    for (int j = t; j < 1024; j += 256) row[j] = (j < 896) ? lqd[j] : 0u;
}

// ===== bit-stats (stride-9 conflict-free reduce) =====
static __device__ __forceinline__ void unpack_acc(u32 v, u32 pk[8]) {
#pragma unroll
    for (int k = 0; k < 8; k++) pk[k] += (v >> k) & 0x01010101u;
}

static __device__ __forceinline__ void reduce_cat(u32* red, int* gdst, const u32 pk[8],
                                                  bool active, int t) {
#pragma unroll
    for (int k = 0; k < 8; k++) red[t * 9 + k] = active ? pk[k] : 0u;
    __syncthreads();
#pragma unroll
    for (int p = t; p < 512; p += 256) {
        int ci = p >> 3, k = p & 7, ci4 = ci >> 2, bb = ci & 3;
        int sum = 0;
#pragma unroll
        for (int xo = 0; xo < 16; xo++)
            sum += (red[(xo * 16 + ci4) * 9 + k] >> (8 * bb)) & 0xFF;
        if (sum) atomicAdd(&gdst[p], sum);
    }
    __syncthreads();
}

// FROMF=0: read packed int8 from qpad (xor xm). FROMF=1: recompute quant from o-row + s1
// (bit-exact with the old stored q1: same fmaxf/rintf/fminf sequence; xor 0x80 of (q-128) == q).
template <int FROMF>
static __device__ __forceinline__ u32 pk_at(const u32* img, const float* ofb, float s1,
                                            u32 xm, int row, int xx, int ci4) {
    if (FROMF) {
        float4 v = *(const float4*)(ofb + (size_t)row * 3584 + xx * 64 + ci4 * 4);
        u32 pk = 0;
#pragma unroll
        for (int i = 0; i < 4; i++) {
            float vv = fmaxf(((const float*)&v)[i], 0.f);
            u32 q = (u32)(int)fminf(rintf(vv / s1), 255.f);
            pk |= q << (8 * i);
        }
        return pk;
    }
    return img[(size_t)row * 1024 + xx * 16 + ci4] ^ xm;
}

// 128 seven-row units: s -> (n = s/8, slab = s%8), rows y0=slab*7..+6
template <int FROMF>
static __device__ void stats_unit(u32* red, const char* qpad, const float* of, float s1,
                                  u32 xorm, int* gst, int s, int t) {
    int n = s >> 3, slab = s & 7;
    int ci4 = t & 15, xo = t >> 4;
    const u32* img = FROMF ? nullptr : (const u32*)(qpad + (size_t)(2 + n * ROWS_PI) * PADROW);
    const float* ofb = FROMF ? (of + (size_t)n * 56 * 3584) : nullptr;
    u32 xm = xorm * 0x01010101u;
    int y0 = slab * 7;
    {   // main total (j=0)
        u32 pk[8] = {0,0,0,0,0,0,0,0};
#pragma unroll
        for (int r = 0; r < 7; r++)
#pragma unroll
            for (int j = 0; j < 4; j++) {
                int xx = xo + 16 * j;
                if (xx < 56) unpack_acc(pk_at<FROMF>(img, ofb, s1, xm, y0 + r, xx, ci4), pk);
            }
        reduce_cat(red, gst + 0 * 512, pk, true, t);
    }
    {   // Cleft (j=3)
        u32 pk[8] = {0,0,0,0,0,0,0,0};
        bool act = (xo == 0);
        if (act)
#pragma unroll
            for (int r = 0; r < 7; r++)
                unpack_acc(pk_at<FROMF>(img, ofb, s1, xm, y0 + r, 0, ci4), pk);
        reduce_cat(red, gst + 3 * 512, pk, act, t);
    }
    {   // Cright (j=4)
        u32 pk[8] = {0,0,0,0,0,0,0,0};
        bool act = (xo == 7);
        if (act)
#pragma unroll
            for (int r = 0; r < 7; r++)
                unpack_acc(pk_at<FROMF>(img, ofb, s1, xm, y0 + r, 55, ci4), pk);
        reduce_cat(red, gst + 4 * 512, pk, act, t);
    }
    if (slab == 0) {   // Rtop (j=1) + corners 5,6
        u32 pk[8] = {0,0,0,0,0,0,0,0};
#pragma unroll
        for (int j = 0; j < 4; j++) {
            int xx = xo + 16 * j;
            if (xx < 56) unpack_acc(pk_at<FROMF>(img, ofb, s1, xm, 0, xx, ci4), pk);
        }
        reduce_cat(red, gst + 1 * 512, pk, true, t);
        if (t < 32) {
            int which = t >> 4, c4 = t & 15;
            u32 v = pk_at<FROMF>(img, ofb, s1, xm, 0, which ? 55 : 0, c4);
            for (int b = 0; b < 4; b++)
                for (int k = 0; k < 8; k++)
                    if ((v >> (8 * b + k)) & 1)
                        atomicAdd(&gst[(5 + which) * 512 + (c4 * 4 + b) * 8 + k], 1);
        }
    }
    if (slab == 7) {   // Rbot (j=2) + corners 7,8
        u32 pk[8] = {0,0,0,0,0,0,0,0};
#pragma unroll
        for (int j = 0; j < 4; j++) {
            int xx = xo + 16 * j;
            if (xx < 56) unpack_acc(pk_at<FROMF>(img, ofb, s1, xm, 55, xx, ci4), pk);
        }
        reduce_cat(red, gst + 2 * 512, pk, true, t);
        if (t < 32) {
            int which = t >> 4, c4 = t & 15;
            u32 v = pk_at<FROMF>(img, ofb, s1, xm, 55, which ? 55 : 0, c4);
            for (int b = 0; b < 4; b++)
                for (int k = 0; k < 8; k++)
                    if ((v >> (8 * b + k)) & 1)
                        atomicAdd(&gst[(7 + which) * 512 + (c4 * 4 + b) * 8 + k], 1);
        }
    }
}

// ===== K3: conv1 (zero-LDS streaming, blocks 0..447) + stats(qx) riders (448..575) =====
__global__ __launch_bounds__(256, 2) void k_conv1(const char* __restrict__ qin,
                                                  const char* __restrict__ qw,
                                                  const float* __restrict__ gg, const float* __restrict__ bb,
                                                  const float* __restrict__ mmp, const float* __restrict__ vvp,
                                                  const float* __restrict__ scal,
                                                  float* __restrict__ outp, u32* __restrict__ rmaxp,
                                                  int* __restrict__ gst) {
    __shared__ union { float red[4]; u32 sred[2304]; } sm;
    int b = blockIdx.x, t = threadIdx.x;
    if (b >= 448) {    // bit-stats rider on qx (xorm 0); qx L2-hot from conv reads
        stats_unit<0>(sm.sred, qin, nullptr, 0.f, 0u, gst, b - 448, t);
        return;
    }
    int w = t >> 6, lane = t & 63, mq = lane & 15, quad = lane >> 4;
    int u0 = b * 2;
    int n = u0 / 56, y = u0 - n * 56;
    const v4i* qin4 = (const v4i*)qin;
    size_t rbase = (size_t)(1 + n * ROWS_PI + y) * 256;
    v4i acc[2][4] = {{{0,0,0,0},{0,0,0,0},{0,0,0,0},{0,0,0,0}},
                     {{0,0,0,0},{0,0,0,0},{0,0,0,0},{0,0,0,0}}};
#pragma unroll
    for (int tap = 0; tap < 9; tap++) {
        const int ky = tap / 3, kx = tap - ky * 3;
        v4i bf[4];
#pragma unroll
        for (int nt = 0; nt < 4; nt++)
            bf[nt] = *(const v4i*)&qw[(size_t)((tap * 64 + nt * 16 + mq) << 6) + quad * 16];
        int px = w * 16 + mq + kx;
#pragma unroll
        for (int rr = 0; rr < 2; rr++) {
            v4i a = qin4[rbase + (size_t)(rr + ky) * 256 - 4 + px * 4 + quad];
#pragma unroll
            for (int nt = 0; nt < 4; nt++)
                acc[rr][nt] = __builtin_amdgcn_mfma_i32_16x16x64_i8(a, bf[nt], acc[rr][nt], 0, 0, 0);
        }
    }
    float sIn = scal[0] / 127.f;
    float sW  = scal[1] / 127.f;
    float alpha[4], beta[4];
#pragma unroll
    for (int nt = 0; nt < 4; nt++) {
        int co = nt * 16 + mq;
        float inv = gg[co] * rsqrtf(vvp[co] + 1e-5f);
        alpha[nt] = sIn * sW * inv;
        beta[nt]  = bb[co] - mmp[co] * inv;
    }
    float lmax = 0.f;
#pragma unroll
    for (int rr = 0; rr < 2; rr++) {
        size_t rowb = (size_t)(u0 + rr) * 3584;
#pragma unroll
        for (int nt = 0; nt < 4; nt++) {
            int co = nt * 16 + mq;
#pragma unroll
            for (int r = 0; r < 4; r++) {
                int xx = w * 16 + quad * 4 + r;
                if (xx < 56) {
                    float o = (float)acc[rr][nt][r] * alpha[nt] + beta[nt];
                    outp[rowb + xx * 64 + co] = o;
                    lmax = fmaxf(lmax, o);
                }
            }
        }
    }
#pragma unroll
    for (int off = 32; off > 0; off >>= 1) lmax = fmaxf(lmax, __shfl_down(lmax, off));
    if (lane == 0) sm.red[w] = lmax;
    __syncthreads();
    if (t == 0)
        atomicMax(rmaxp, __float_as_uint(fmaxf(fmaxf(sm.red[0], sm.red[1]),
                                               fmaxf(sm.red[2], sm.red[3]))));
}

// ===== K4: conv2 FUSED with quant_relu1 — halo rows recomputed from o1 into LDS
// (bit-exact with the old q1 path), + stats FROMF(o1) riders. q1 never materialized. =====
__global__ __launch_bounds__(256, 2) void k_conv2f(const float* __restrict__ o1,
                                                   const char* __restrict__ qw,
                                                   const int* __restrict__ wsum9,
                                                   const char* __restrict__ qid,
                                                   const float* __restrict__ gg, const float* __restrict__ bb,
                                                   const float* __restrict__ mmp, const float* __restrict__ vvp,
                                                   const float* __restrict__ scal,
                                                   float* __restrict__ outp, u32* __restrict__ rmaxp,
                                                   int* __restrict__ gst) {
    __shared__ union { struct { u32 lin[5280]; float red[4]; } c; u32 sred[2304]; } sm;
    int b = blockIdx.x, t = threadIdx.x;
    float s1 = __uint_as_float(((const u32*)scal)[32]) / 255.f;
    if (b >= 448) {    // stats rider: q1-equivalent recomputed from o1 (R8-verified FROMF path)
        stats_unit<1>(sm.sred, nullptr, o1, s1, 0u, gst, b - 448, t);
        return;
    }
    int w = t >> 6, lane = t & 63, mq = lane & 15, quad = lane >> 4;
    int u0 = b * 2;
    int n = u0 / 56, y = u0 - n * 56;
    // LDS tile [4 rows][66 px][20 dw] <- quantized o1 rows y-1..y+2 (pads = -128 byte)
    for (int j = t; j < 5280; j += 256) sm.c.lin[j] = 0x80808080u;
    __syncthreads();
    for (int j = t; j < 3584; j += 256) {   // 4 rows x 896 float4
        int lr = j >> 10;                   // NOTE: 896 per row -> use div
        lr = j / 896;
        int r = j - lr * 896;
        int ry = y - 1 + lr;
        if (ry >= 0 && ry <= 55) {
            int px = r >> 4, cd = r & 15;
            float4 v = *(const float4*)(o1 + (size_t)(n * 56 + ry) * 3584 + (px << 6) + (cd << 2));
            u32 pk = 0;
#pragma unroll
            for (int i = 0; i < 4; i++) {
                float vv = fmaxf(((const float*)&v)[i], 0.f);
                float q = fminf(rintf(vv / s1), 255.f);
                pk |= ((u32)(unsigned char)(char)((int)q - 128)) << (8 * i);
            }
            sm.c.lin[(lr * 66 + px + 1) * 20 + cd] = pk;
        }
    }
    __syncthreads();
    v4i acc[2][4] = {{{0,0,0,0},{0,0,0,0},{0,0,0,0},{0,0,0,0}},
                     {{0,0,0,0},{0,0,0,0},{0,0,0,0},{0,0,0,0}}};
#pragma unroll
    for (int tap = 0; tap < 9; tap++) {
        const int ky = tap / 3, kx = tap - ky * 3;
        v4i bf[4];
#pragma unroll
        for (int nt = 0; nt < 4; nt++)
            bf[nt] = *(const v4i*)&qw[(size_t)((tap * 64 + nt * 16 + mq) << 6) + quad * 16];
        int px = w * 16 + mq + kx;
#pragma unroll
        for (int rr = 0; rr < 2; rr++) {
            v4i a = *(const v4i*)&sm.c.lin[((rr + ky) * 66 + px) * 20 + quad * 4];
#pragma unroll
            for (int nt = 0; nt < 4; nt++)
                acc[rr][nt] = __builtin_amdgcn_mfma_i32_16x16x64_i8(a, bf[nt], acc[rr][nt], 0, 0, 0);
        }
    }
    float sIn = s1;
    float sW  = scal[2] / 127.f;
    float sx  = scal[0] / 127.f;
    float alpha[4], beta[4]; int wofs[4];
#pragma unroll
    for (int nt = 0; nt < 4; nt++) {
        int co = nt * 16 + mq;
        float inv = gg[co] * rsqrtf(vvp[co] + 1e-5f);
        alpha[nt] = sIn * sW * inv;
        beta[nt]  = bb[co] - mmp[co] * inv;
        int ws9 = 0;
#pragma unroll
        for (int kp = 0; kp < 9; kp++) ws9 += wsum9[kp * 64 + co];
        wofs[nt] = ws9 << 7;
    }
    float lmax = 0.f;
#pragma unroll
    for (int rr = 0; rr < 2; rr++) {
        int yr = y + rr;
        size_t rowb = (size_t)(u0 + rr) * 3584;
        const signed char* idrow =
            (const signed char*)(qid + (size_t)(2 + n * ROWS_PI + yr) * PADROW);
#pragma unroll
        for (int nt = 0; nt < 4; nt++) {
            int co = nt * 16 + mq;
#pragma unroll
            for (int r = 0; r < 4; r++) {
                int xx = w * 16 + quad * 4 + r;
                if (xx < 56) {
                    float o = (float)(acc[rr][nt][r] + wofs[nt]) * alpha[nt] + beta[nt];
                    o += sx * (float)idrow[xx * 64 + co];
                    outp[rowb + xx * 64 + co] = o;
                    lmax = fmaxf(lmax, o);
                }
            }
        }
    }
#pragma unroll
    for (int off = 32; off > 0; off >>= 1) lmax = fmaxf(lmax, __shfl_down(lmax, off));
    if (lane == 0) sm.c.red[w] = lmax;
    __syncthreads();
    if (t == 0)
        atomicMax(rmaxp, __float_as_uint(fmaxf(fmaxf(sm.c.red[0], sm.c.red[1]),
                                               fmaxf(sm.c.red[2], sm.c.red[3]))));
}

// ===== K5: final quantize + NHWC->NCHW (2 rows/block) + HM tail block =====
__global__ __launch_bounds__(256) void k_final(const float* __restrict__ o2,
                                               const float* __restrict__ scal,
                                               float* __restrict__ outp,
                                               const int* __restrict__ stx, const int* __restrict__ stq,
                                               const int* __restrict__ wb1, const int* __restrict__ wb2) {
    __shared__ union { float lt[64 * 57]; long long r1[256]; } sm;
    int b = blockIdx.x, t = threadIdx.x;
    if (b == 448) {    // HM combine
        long long act = 0, en = 0;
#pragma unroll
        for (int half = 0; half < 2; half++) {
            int tt = t + half * 256;   // tt = ci*8 + k
#pragma unroll
            for (int wsel = 0; wsel < 2; wsel++) {
                const int* st = wsel ? stq : stx;
                const int* wb = wsel ? wb2 : wb1;
                long long s[9];
#pragma unroll
                for (int j = 0; j < 9; j++) s[j] = st[j * 512 + tt];
                int wr[9];
#pragma unroll
                for (int j = 0; j < 9; j++) wr[j] = wb[tt * 9 + j];
                long long wall = 0;
#pragma unroll
                for (int j = 0; j < 9; j++) wall += wr[j];
                long long wr0 = (long long)wr[0] + wr[1] + wr[2];
                long long wr2 = (long long)wr[6] + wr[7] + wr[8];
                long long wc0 = (long long)wr[0] + wr[3] + wr[6];
                long long wc2 = (long long)wr[2] + wr[5] + wr[8];
                en += s[0] * wall - s[1] * wr2 - s[2] * wr0 - s[3] * wc2 - s[4] * wc0
                    + s[5] * (long long)wr[8] + s[6] * (long long)wr[6]
                    + s[7] * (long long)wr[2] + s[8] * (long long)wr[0];
                act += s[0];
            }
        }
        sm.r1[t] = en; __syncthreads();
        for (int s = 128; s > 0; s >>= 1) { if (t < s) sm.r1[t] += sm.r1[t + s]; __syncthreads(); }
        long long etot = sm.r1[0]; __syncthreads();
        sm.r1[t] = act; __syncthreads();
        for (int s = 128; s > 0; s >>= 1) { if (t < s) sm.r1[t] += sm.r1[t + s]; __syncthreads(); }
        if (t == 0) {
            outp[OUTN]     = (float)sm.r1[0];   // HM_act
            outp[OUTN + 1] = (float)etot;       // HM_energy
        }
        return;
    }
    float s2 = __uint_as_float(((const u32*)scal)[64]) / 255.f;
#pragma unroll
    for (int rr = 0; rr < 2; rr++) {
        int u = b * 2 + rr;
        int n = u / 56, y = u - n * 56;
        __syncthreads();
        const float4* o4 = (const float4*)(o2 + (size_t)u * 3584);
        for (int j = t; j < 896; j += 256) {      // 56 xx x 16 c4-groups
            int xx = j >> 4, c4 = j & 15;
            float4 v = o4[j];
#pragma unroll
            for (int i = 0; i < 4; i++) {
                float vv = fmaxf(((const float*)&v)[i], 0.f);
                float q = fminf(rintf(vv / s2), 255.f);
                sm.lt[(4 * c4 + i) * 57 + xx] = q * s2;
            }
        }
        __syncthreads();
        for (int idx = t; idx < 3584; idx += 256) {
            int co = idx / 56, xx = idx - co * 56;
            outp[(size_t)n * 200704 + (size_t)co * 3136 + y * 56 + xx] = sm.lt[co * 57 + xx];
        }
    }
}

extern "C" void kernel_launch(void* const* d_in, const int* in_sizes, int n_in,
                              void* d_out, int out_size, void* d_ws, size_t ws_size,
                              hipStream_t stream) {
    if (ws_size < WS_NEED) return;
    const float* x  = (const float*)d_in[0];
    const float* w1 = (const float*)d_in[1];
    const float* w2 = (const float*)d_in[2];
    const float* g1 = (const float*)d_in[3];
    const float* b1 = (const float*)d_in[4];
    const float* m1 = (const float*)d_in[5];
    const float* v1 = (const float*)d_in[6];
    const float* g2 = (const float*)d_in[7];
    const float* b2 = (const float*)d_in[8];
    const float* m2 = (const float*)d_in[9];
    const float* v2 = (const float*)d_in[10];
    char* ws = (char*)d_ws;
    char* qx  = ws + OFS_QX;
    float* o1 = (float*)(ws + OFS_O1);
    float* o2 = (float*)(ws + OFS_O2);
    char* qw1 = ws + OFS_QW1;
    char* qw2 = ws + OFS_QW2;
    int* wb1  = (int*)(ws + OFS_WB1);
    int* wb2  = (int*)(ws + OFS_WB2);
    int* wsum9= (int*)(ws + OFS_WSUM);
    float* scal = (float*)(ws + OFS_SCAL);
    u32* rmax1 = (u32*)(ws + OFS_SCAL + 128);
    u32* rmax2 = (u32*)(ws + OFS_SCAL + 256);
    int* stx  = (int*)(ws + OFS_STX);
    int* stq  = (int*)(ws + OFS_STQ);
    float* wsred = (float*)(ws + OFS_WSRED);
    float* outp = (float*)d_out;

    k_absmax_qw<<<1042, 256, 0, stream>>>(x, w1, w2, qw1, qw2, wb1, wb2,
                                          wsum9, scal, wsred, stx, stq);
    k_quant_x<<<dim3(16, 58), 256, 0, stream>>>(x, qx, wsred, scal);
    k_conv1<<<576, 256, 0, stream>>>(qx, qw1, g1, b1, m1, v1, scal, o1, rmax1, stx);
    k_conv2f<<<576, 256, 0, stream>>>(o1, qw2, wsum9, qx, g2, b2, m2, v2,
                                      scal, o2, rmax2, stq);
    k_final<<<449, 256, 0, stream>>>(o2, scal, outp, stx, stq, wb1, wb2);
}